// Round 18
// baseline (1505.696 us; speedup 1.0000x reference)
//
#include <hip/hip_runtime.h>
#include <math.h>

#define NUM_E 65536
#define NUM_N 8192
#define NUM_G 16
#define RBFR 12.0f

typedef unsigned short u16;
typedef _Float16 f16x8 __attribute__((ext_vector_type(8)));
typedef _Float16 f16x4 __attribute__((ext_vector_type(4)));
typedef float f32x4 __attribute__((ext_vector_type(4)));

// ---------------- packed-weight geometry: [128n][64k] tiles, plain 128-col groups ----------------
#define TILE_F16 8192
#define L1SZ   1114112   // 8 bn * 17 kt * 8192
#define HSZ    1048576   // 8 bn * 16 kt * 8192 per layer
#define MSTRIDE 4259840  // L1SZ + 3*HSZ

// fused-fallback packed geometry
#define FU1  139264
#define FUHL 131072
#define FUPM (FU1 + 3 * FUHL)

#define GLD16(gp, lp) __builtin_amdgcn_global_load_lds( \
    (const __attribute__((address_space(1))) void*)(gp), \
    (__attribute__((address_space(3))) void*)(lp), 16, 0, 0)

// ---------- pre-kernel: W_rbf = rbf_w @ in_w[1024:1536,:]; b1 folded
__global__ void wrbf_kernel(const float* __restrict__ rbf_w, const float* __restrict__ rbf_b,
                            const float* __restrict__ e_in_w, const float* __restrict__ e_in_b,
                            const float* __restrict__ f_in_w, const float* __restrict__ f_in_b,
                            float* __restrict__ wrbf_e, float* __restrict__ b1_e,
                            float* __restrict__ wrbf_f, float* __restrict__ b1_f) {
  int blk = blockIdx.x;            // 408 = 2mlp * 51row * 4ns
  int mlp = blk / 204;
  int rr = blk % 204;
  int row = rr >> 2;
  int ns = rr & 3;
  const float* in_w = mlp ? f_in_w : e_in_w;
  const float* in_b = mlp ? f_in_b : e_in_b;
  float* wrbf = mlp ? wrbf_f : wrbf_e;
  float* b1   = mlp ? b1_f : b1_e;
  __shared__ float vec[512];
  __shared__ float4 red[256];
  int tid = threadIdx.x;
  vec[tid]       = (row < 50) ? rbf_w[row * 512 + tid]       : rbf_b[tid];
  vec[tid + 256] = (row < 50) ? rbf_w[row * 512 + tid + 256] : rbf_b[tid + 256];
  __syncthreads();
  int q = tid >> 6, l = tid & 63;
  int n0 = ns * 256 + l * 4;
  float a0 = 0.f, a1 = 0.f, a2 = 0.f, a3 = 0.f;
#pragma unroll 4
  for (int c = q * 128; c < q * 128 + 128; ++c) {
    float4 wv = *(const float4*)&in_w[(size_t)(1024 + c) * 1024 + n0];
    float gv = vec[c];
    a0 += gv * wv.x; a1 += gv * wv.y; a2 += gv * wv.z; a3 += gv * wv.w;
  }
  red[tid] = float4{a0, a1, a2, a3};
  __syncthreads();
  if (q == 0) {
    float4 s0 = red[l], s1 = red[l + 64], s2 = red[l + 128], s3 = red[l + 192];
    float4 o = {s0.x + s1.x + s2.x + s3.x, s0.y + s1.y + s2.y + s3.y,
                s0.z + s1.z + s2.z + s3.z, s0.w + s1.w + s2.w + s3.w};
    if (row < 50) {
      *(float4*)&wrbf[row * 1024 + n0] = o;
    } else {
      o.x += in_b[n0]; o.y += in_b[n0 + 1]; o.z += in_b[n0 + 2]; o.w += in_b[n0 + 3];
      *(float4*)&b1[n0] = o;
    }
  }
}

// ---------- merged prep: x->f16 (bid<4096) + per-edge RBF table (else)
__global__ void prep_kernel(const float* __restrict__ x, const float* __restrict__ dist,
                            u16* __restrict__ xh, u16* __restrict__ grbf) {
  int bid = blockIdx.x, tid = threadIdx.x;
  if (bid < 4096) {
    int i = bid * 256 + tid;
    float4 v = ((const float4*)x)[i];
    f16x4 h = {(_Float16)v.x, (_Float16)v.y, (_Float16)v.z, (_Float16)v.w};
    *(f16x4*)(xh + (size_t)i * 4) = h;
  } else {
    int u = (bid - 4096) * 256 + tid;
    int e = u >> 3, q = u & 7;
    const float delta = RBFR / 49.f;
    const float coeff = -0.5f / (delta * delta);
    float d = dist[e];
    f16x8 h;
#pragma unroll
    for (int j = 0; j < 8; ++j) {
      int gi = q * 8 + j;
      float dd = d - (float)gi * delta;
      float gg = (gi < 50) ? __expf(coeff * dd * dd) : 0.f;
      h[j] = (_Float16)gg;
    }
    *(f16x8*)(grbf + (size_t)u * 8) = h;
  }
}

// ---------- weight pack v5: plain 128-col tiles, float4 row-coalesced reads, LDS build
__global__ void pack_gemm(const float* __restrict__ e_in_w, const float* __restrict__ e_hid_w,
                          const float* __restrict__ f_in_w, const float* __restrict__ f_hid_w,
                          const float* __restrict__ wrbf_e, const float* __restrict__ wrbf_f,
                          u16* __restrict__ wp) {
  __shared__ __align__(16) u16 tile[TILE_F16];
  int bid = blockIdx.x;                  // 1040 = 2 mlp * (136 l1 + 384 hidden)
  int mlpi = (bid >= 520) ? 1 : 0;
  int t = bid - mlpi * 520;
  const float* in_w  = mlpi ? f_in_w : e_in_w;
  const float* hid_w = mlpi ? f_hid_w : e_hid_w;
  const float* wrbf  = mlpi ? wrbf_f : wrbf_e;
  int tid = threadIdx.x;
  int bn, k0, lay = 0, is_l1;
  if (t < 136) {
    bn = t / 17; k0 = (t % 17) * 64; is_l1 = 1;
  } else {
    int th = t - 136; lay = th >> 7; int r = th & 127;
    bn = r >> 4; k0 = (r & 15) * 64; is_l1 = 0;
  }
#pragma unroll
  for (int it = 0; it < 8; ++it) {
    int flat = it * 1024 + tid * 4;      // tile elem = k*128 + nl
    int k = flat >> 7;
    int nl4 = flat & 127;
    int n0 = bn * 128 + nl4;
    int kg = k0 + k;
    float4 v;
    if (is_l1) {
      if (kg < 1024)      v = *(const float4*)&in_w[(size_t)kg * 1024 + n0];
      else if (kg < 1074) v = *(const float4*)&wrbf[(size_t)(kg - 1024) * 1024 + n0];
      else                v = float4{0.f, 0.f, 0.f, 0.f};
    } else {
      v = *(const float4*)&hid_w[(size_t)((lay << 10) + kg) * 1024 + n0];
    }
#pragma unroll
    for (int c = 0; c < 4; ++c) {
      int nl = nl4 + c;
      int pos = nl * 64 + ((((k >> 3) ^ (nl & 7)) << 3) | (k & 7));
      _Float16 hf = (_Float16)(((const float*)&v)[c]);
      tile[pos] = __builtin_bit_cast(u16, hf);
    }
  }
  __syncthreads();
  u16* dst = wp + (size_t)mlpi * MSTRIDE + (size_t)t * TILE_F16;
#pragma unroll
  for (int i = 0; i < 4; ++i) {
    int off = (i * 256 + tid) * 8;
    *(f16x8*)(dst + off) = *(const f16x8*)(tile + off);
  }
}

// ================= m97-structure 128x128 GEMM, BK=64, 4 waves, single-buffered =================
// MODE: 1 = layer-1 (gathered A, offsets hoisted), 0 = hidden mid, 2 = final+scatter.
// Per wave quadrant 64x64 (wm=wv>>1, wn=wv&1), acc[4][4] f32x4 (64 VGPR).
// K-loop: stage A+B (8 gld/thread total across block) -> __syncthreads (drain)
// -> 16 ds_read_b128 + 32 MFMA per wave -> __syncthreads. TLP (3 blocks/CU) hides drains.

#define STA(kt) do { \
  _Pragma("unroll") for (int _u = 0; _u < 4; ++_u) { \
    int _c = _u * 4 + wv; \
    const u16* _gp; \
    if (MODE == 1) { \
      int _off = ((kt) < 8) ? (osrc[_u] + (kt) * 64) \
               : (((kt) < 16) ? (odst[_u] + ((kt) - 8) * 64) : ogr[_u]); \
      _gp = (((kt) < 16) ? hin : grbf) + _off; \
    } else { \
      int _row = _c * 8 + (lane >> 3); \
      int _sw = ((lane & 7) ^ (_row & 7)) << 3; \
      _gp = hin + ((size_t)(rowb + _row) * 1024 + (kt) * 64 + _sw); \
    } \
    GLD16(_gp, (char*)As + _c * 1024); \
  } \
} while (0)

#define STB(kt) do { \
  const u16* _wt = wl + ((size_t)(bn * NKT + (kt))) * TILE_F16; \
  _Pragma("unroll") for (int _u = 0; _u < 4; ++_u) { \
    int _c = _u * 4 + wv; \
    GLD16(_wt + _c * 512 + lane * 8, (char*)Bs + _c * 1024); \
  } \
} while (0)

#define RDAB() do { \
  _Pragma("unroll") for (int _ks = 0; _ks < 2; ++_ks) { \
    int _kk = _ks * 4 + (lane >> 4); \
    _Pragma("unroll") for (int _m = 0; _m < 4; ++_m) { \
      int _r = wm * 64 + _m * 16 + (lane & 15); \
      af[_m][_ks] = *(const f16x8*)&As[_r * 64 + ((_kk ^ (_r & 7)) << 3)]; \
    } \
    _Pragma("unroll") for (int _n = 0; _n < 4; ++_n) { \
      int _cc = wn * 64 + _n * 16 + (lane & 15); \
      bf[_n][_ks] = *(const f16x8*)&Bs[_cc * 64 + ((_kk ^ (_cc & 7)) << 3)]; \
    } \
  } \
} while (0)

#define MFMAS() do { \
  __builtin_amdgcn_s_setprio(1); \
  _Pragma("unroll") for (int _ks = 0; _ks < 2; ++_ks) \
    _Pragma("unroll") for (int _m = 0; _m < 4; ++_m) \
      _Pragma("unroll") for (int _n = 0; _n < 4; ++_n) \
        acc[_m][_n] = __builtin_amdgcn_mfma_f32_16x16x32_f16( \
            bf[_n][_ks], af[_m][_ks], acc[_m][_n], 0, 0, 0); \
  __builtin_amdgcn_s_setprio(0); \
} while (0)

template<int NKT, int MODE>
__global__ __launch_bounds__(256, 3) void gemm8k(
    const u16* __restrict__ hinE, const u16* __restrict__ hinF,
    const u16* __restrict__ grbf, const int* __restrict__ eidx,
    const int* __restrict__ batch, const float* __restrict__ vhat,
    const u16* __restrict__ wp, size_t woff,
    const float* __restrict__ biasE, const float* __restrict__ biasF,
    u16* __restrict__ houtE, u16* __restrict__ houtF,
    const float* __restrict__ owE, const float* __restrict__ owF,
    const float* __restrict__ obE, const float* __restrict__ obF,
    float* __restrict__ out, int mstart) {
  __shared__ __align__(16) u16 As[128 * 64];   // 16 KiB
  __shared__ __align__(16) u16 Bs[128 * 64];   // 16 KiB
  __shared__ int s_src[128];
  __shared__ int s_dst[128];
  __shared__ float sred[128];
  __shared__ float sbins[16];
  const int tid = threadIdx.x;
  const int lane = tid & 63;
  const int wv = tid >> 6;
  const int wm = wv >> 1, wn = wv & 1;

  // XCD-locality decode: xcd = mt&7; all 16 (bn,mlp) siblings of mt share the XCD.
  const int xcd = blockIdx.x & 7;
  const int r = blockIdx.x >> 3;
  const int bn = r & 7;
  const int mlp = (r >> 3) & 1;
  const int mt = (r >> 4) * 8 + xcd;

  const u16* hin = (MODE == 1) ? hinE : (mlp ? hinF : hinE);
  const u16* wl = wp + (size_t)mlp * MSTRIDE + woff;
  const float* bias = mlp ? biasF : biasE;
  u16* hout = mlp ? houtF : houtE;
  const int rowb = mt * 128;
  const int n0 = bn * 128;
  const int eg0 = mstart + rowb;

  int osrc[4], odst[4], ogr[4];
  if (MODE == 1) {
    if (tid < 128) { s_src[tid] = eidx[eg0 + tid]; }
    else { s_dst[tid - 128] = eidx[NUM_E + eg0 + tid - 128]; }
    __syncthreads();
#pragma unroll
    for (int u = 0; u < 4; ++u) {
      int c = u * 4 + wv;
      int row = c * 8 + (lane >> 3);
      int sw = ((lane & 7) ^ (row & 7)) << 3;
      osrc[u] = s_src[row] * 512 + sw;
      odst[u] = s_dst[row] * 512 + sw;
      ogr[u]  = (eg0 + row) * 64 + sw;
    }
  }

  f32x4 acc[4][4];
#pragma unroll
  for (int m = 0; m < 4; ++m)
#pragma unroll
    for (int n = 0; n < 4; ++n)
#pragma unroll
      for (int i = 0; i < 4; ++i) acc[m][n][i] = 0.f;

  f16x8 af[4][2], bf[4][2];

  for (int kt = 0; kt < NKT; ++kt) {
    STA(kt); STB(kt);
    __syncthreads();          // drains vmcnt(0): staged tile visible
    RDAB();
    MFMAS();
    __syncthreads();          // all reads done before next stage overwrites
  }

  if (MODE != 2) {
    // epilogue: bias + silu (+ residual for hidden), store f16
#pragma unroll
    for (int m = 0; m < 4; ++m) {
      int grow = rowb + wm * 64 + m * 16 + (lane & 15);
#pragma unroll
      for (int n = 0; n < 4; ++n) {
        int gn = n0 + wn * 64 + n * 16 + ((lane >> 4) << 2);
        float4 bi = *(const float4*)&bias[gn];
        f16x4 o;
        if (MODE == 1) {
#pragma unroll
          for (int i = 0; i < 4; ++i) {
            float pre = acc[m][n][i] + ((const float*)&bi)[i];
            o[i] = (_Float16)(pre / (1.f + __expf(-pre)));
          }
        } else {
          f16x4 hp = *(const f16x4*)&hin[(size_t)grow * 1024 + gn];
#pragma unroll
          for (int i = 0; i < 4; ++i) {
            float pre = acc[m][n][i] + ((const float*)&bi)[i];
            o[i] = (_Float16)(pre / (1.f + __expf(-pre)) + (float)hp[i]);
          }
        }
        *(f16x4*)&hout[(size_t)grow * 1024 + gn] = o;
      }
    }
  } else {
    // fused final epilogue: silu+residual, dot with out_w, reduce, scatter
    if (tid < 128) sred[tid] = 0.f;
    if (tid < 16) sbins[tid] = 0.f;
    __syncthreads();
    const float* ow = mlp ? owF : owE;
    float p[4];
#pragma unroll
    for (int m = 0; m < 4; ++m) p[m] = 0.f;
#pragma unroll
    for (int m = 0; m < 4; ++m) {
      int grow = rowb + wm * 64 + m * 16 + (lane & 15);
#pragma unroll
      for (int n = 0; n < 4; ++n) {
        int gn = n0 + wn * 64 + n * 16 + ((lane >> 4) << 2);
        float4 bi = *(const float4*)&bias[gn];
        float4 wv4 = *(const float4*)&ow[gn];
        f16x4 hp = *(const f16x4*)&hin[(size_t)grow * 1024 + gn];
#pragma unroll
        for (int i = 0; i < 4; ++i) {
          float pre = acc[m][n][i] + ((const float*)&bi)[i];
          float val = pre / (1.f + __expf(-pre)) + (float)hp[i];
          p[m] += val * ((const float*)&wv4)[i];
        }
      }
    }
#pragma unroll
    for (int m = 0; m < 4; ++m) {
      p[m] += __shfl_down(p[m], 32, 64);
      p[m] += __shfl_down(p[m], 16, 64);
    }
    if ((lane >> 4) == 0) {
#pragma unroll
      for (int m = 0; m < 4; ++m)
        atomicAdd(&sred[wm * 64 + m * 16 + (lane & 15)], p[m]);
    }
    __syncthreads();
    if (tid < 128) {
      float s = sred[tid];
      int eg = eg0 + tid;
      int si = eidx[eg];
      if (mlp == 0) {
        float pv = s + ((bn == 0) ? obE[0] : 0.f);
        atomicAdd(&sbins[batch[si]], pv);
      } else {
        float pv = (s + ((bn == 0) ? obF[0] : 0.f)) * (1.f / 60.f);
        atomicAdd(&out[16 + si * 3 + 0], pv * vhat[(size_t)eg * 3 + 0]);
        atomicAdd(&out[16 + si * 3 + 1], pv * vhat[(size_t)eg * 3 + 1]);
        atomicAdd(&out[16 + si * 3 + 2], pv * vhat[(size_t)eg * 3 + 2]);
      }
    }
    __syncthreads();
    if (mlp == 0 && tid < 16) atomicAdd(&out[tid], sbins[tid] * (1.f / 3600.f));
  }
}

// ================= fused fallback (only if ws too small) =================
#define FSWZ(row, col) ((((row) * 1088) + (col)) ^ (((row) & 7) << 3))

__global__ void packF_kernel(const float* __restrict__ e_in_w, const float* __restrict__ e_hid_w,
                             const float* __restrict__ f_in_w, const float* __restrict__ f_hid_w,
                             const float* __restrict__ wrbf_e, const float* __restrict__ wrbf_f,
                             u16* __restrict__ wp) {
  int u = blockIdx.x * 256 + threadIdx.x;
  if (u >= 2 * FUPM) return;
  int m = (u >= FUPM) ? 1 : 0;
  int v = u - m * FUPM;
  const float* in_w  = m ? f_in_w : e_in_w;
  const float* hid_w = m ? f_hid_w : e_hid_w;
  const float* wrbf  = m ? wrbf_f : wrbf_e;
  int l = v & 63;
  int kb = (l >> 4) << 3;
  f16x8 vals;
  if (v < FU1) {
    int kt = v >> 12;
    int ntg = (v >> 6) & 63;
    int n = ntg * 16 + (l & 15);
    int k0 = kt * 32 + kb;
#pragma unroll
    for (int jj = 0; jj < 8; ++jj) {
      int k = k0 + jj;
      float f = (k < 1024) ? in_w[(size_t)k * 1024 + n]
              : ((k < 1074) ? wrbf[(k - 1024) * 1024 + n] : 0.f);
      vals[jj] = (_Float16)f;
    }
  } else {
    int vh = v - FU1;
    int lay = vh >> 17;
    int kt = (vh >> 12) & 31;
    int ntg = (vh >> 6) & 63;
    int n = ntg * 16 + (l & 15);
    int k0 = kt * 32 + kb;
#pragma unroll
    for (int jj = 0; jj < 8; ++jj)
      vals[jj] = (_Float16)hid_w[(size_t)((lay << 10) + k0 + jj) * 1024 + n];
  }
  *(f16x8*)(wp + (size_t)u * 8) = vals;
}

#define F_LOADB(buf, kt) do { \
  const u16* _wr = wl + ((size_t)((kt) * 64 + wave * 8) * 64 + lane) * 8; \
  _Pragma("unroll") \
  for (int _nt = 0; _nt < 8; ++_nt) buf[_nt] = *(const f16x8*)(_wr + (size_t)_nt * 512); \
} while (0)
#define F_LOADA(buf, kt) do { \
  const int _kb = (kt) * 32 + ((lane >> 4) << 3); \
  _Pragma("unroll") \
  for (int _r = 0; _r < 4; ++_r) buf[_r] = *(const f16x8*)&Alds[FSWZ(_r * 16 + (lane & 15), _kb)]; \
} while (0)
#define F_MFMAS(abuf, bbuf) do { \
  _Pragma("unroll") \
  for (int _nt = 0; _nt < 8; ++_nt) \
    _Pragma("unroll") \
    for (int _r = 0; _r < 4; ++_r) \
      acc[_r][_nt] = __builtin_amdgcn_mfma_f32_16x16x32_f16(abuf[_r], bbuf[_nt], acc[_r][_nt], 0, 0, 0); \
} while (0)

__global__ __launch_bounds__(512, 2) void fusedF_kernel(
    const float* __restrict__ x, const int* __restrict__ eidx,
    const int* __restrict__ batch, const float* __restrict__ dist,
    const float* __restrict__ vhat,
    const u16* __restrict__ wp,
    const float* __restrict__ b1_e, const float* __restrict__ b1_f,
    const float* __restrict__ e_hid_b, const float* __restrict__ f_hid_b,
    const float* __restrict__ e_out_w, const float* __restrict__ e_out_b,
    const float* __restrict__ f_out_w, const float* __restrict__ f_out_b,
    float* __restrict__ out) {
  __shared__ __align__(16) u16 Alds[64 * 1088];
  __shared__ float sow[1024];
  __shared__ float sbins[16];
  __shared__ int s_src[64];
  __shared__ int s_dst[64];
  __shared__ float s_dist[64];
  const int tid = threadIdx.x;
  const int lane = tid & 63;
  const int wave = tid >> 6;
  const int e0 = blockIdx.x * 64;
  if (tid < 16) sbins[tid] = 0.f;
  if (tid < 64) s_src[tid] = eidx[e0 + tid];
  if (tid >= 64 && tid < 128) s_dst[tid - 64] = eidx[NUM_E + e0 + tid - 64];
  if (tid >= 128 && tid < 192) s_dist[tid - 128] = dist[e0 + tid - 128];
  __syncthreads();
  const float delta = RBFR / 49.f;
  const float coeff = -0.5f / (delta * delta);
  for (int mlp = 0; mlp < 2; ++mlp) {
    for (int i = tid; i < 16384; i += 512) {
      int e = i >> 8;
      int part = (i >> 7) & 1;
      int q = i & 127;
      int nrow = part ? s_dst[e] : s_src[e];
      float4 v = ((const float4*)x)[(size_t)nrow * 128 + q];
      int col = part * 512 + q * 4;
      f16x4 hv = {(_Float16)v.x, (_Float16)v.y, (_Float16)v.z, (_Float16)v.w};
      *(f16x4*)&Alds[FSWZ(e, col)] = hv;
    }
    for (int i = tid; i < 4096; i += 512) {
      int e = i >> 6;
      int gi = i & 63;
      float d = s_dist[e] - (float)gi * delta;
      float g2 = (gi < 50) ? __expf(coeff * d * d) : 0.f;
      _Float16 hg = (_Float16)g2;
      Alds[FSWZ(e, 1024 + gi)] = __builtin_bit_cast(u16, hg);
    }
    __syncthreads();
    const u16* wp1 = wp + (size_t)mlp * FUPM * 8;
    const u16* wph = wp1 + (size_t)FU1 * 8;
    const float* b1 = mlp ? b1_f : b1_e;
    const float* hb = mlp ? f_hid_b : e_hid_b;
    for (int layer = 0; layer < 4; ++layer) {
      const int nkt = (layer == 0) ? 34 : 32;
      const u16* wl = (layer == 0) ? wp1 : (wph + (size_t)(layer - 1) * FUHL * 8);
      const float* bias = (layer == 0) ? b1 : (hb + (layer - 1) * 1024);
      f32x4 acc[4][8];
#pragma unroll
      for (int r = 0; r < 4; ++r)
#pragma unroll
        for (int nt = 0; nt < 8; ++nt)
#pragma unroll
          for (int i = 0; i < 4; ++i) acc[r][nt][i] = 0.f;
      f16x8 a0[4], a1[4], b0[8], b1r[8];
      F_LOADA(a0, 0); F_LOADB(b0, 0);
      F_LOADA(a1, 1); F_LOADB(b1r, 1);
      for (int kt = 0; kt < nkt; kt += 2) {
        F_MFMAS(a0, b0);
        if (kt + 2 < nkt) { F_LOADA(a0, kt + 2); F_LOADB(b0, kt + 2); }
        F_MFMAS(a1, b1r);
        if (kt + 3 < nkt) { F_LOADA(a1, kt + 3); F_LOADB(b1r, kt + 3); }
      }
      __syncthreads();
      float bia[8];
#pragma unroll
      for (int nt = 0; nt < 8; ++nt) bia[nt] = bias[wave * 128 + nt * 16 + (lane & 15)];
#pragma unroll
      for (int r = 0; r < 4; ++r) {
#pragma unroll
        for (int nt = 0; nt < 8; ++nt) {
#pragma unroll
          for (int i = 0; i < 4; ++i) {
            int row = r * 16 + ((lane >> 4) << 2) + i;
            int col = wave * 128 + nt * 16 + (lane & 15);
            float pre = acc[r][nt][i] + bia[nt];
            float val = pre / (1.f + __expf(-pre));
            int idx = FSWZ(row, col);
            if (layer > 0) {
              _Float16 oldh = __builtin_bit_cast(_Float16, Alds[idx]);
              val += (float)oldh;
            }
            _Float16 nh = (_Float16)val;
            Alds[idx] = __builtin_bit_cast(u16, nh);
          }
        }
      }
      __syncthreads();
    }
    const float* ow = mlp ? f_out_w : e_out_w;
    for (int i = tid; i < 1024; i += 512) sow[i] = ow[i];
    __syncthreads();
    {
      int e = tid >> 3;
      int part = tid & 7;
      float s = 0.f;
#pragma unroll
      for (int cc = 0; cc < 16; ++cc) {
        int col = part * 128 + cc * 8;
        f16x8 hv = *(const f16x8*)&Alds[FSWZ(e, col)];
#pragma unroll
        for (int q = 0; q < 8; ++q) s += (float)hv[q] * sow[col + q];
      }
      s += __shfl_down(s, 4, 8);
      s += __shfl_down(s, 2, 8);
      s += __shfl_down(s, 1, 8);
      if (part == 0) {
        if (mlp == 0) {
          float pp = s + e_out_b[0];
          int gg = batch[s_src[e]];
          atomicAdd(&sbins[gg], pp);
        } else {
          float pp = (s + f_out_b[0]) * (1.f / 60.f);
          int si = s_src[e];
          atomicAdd(&out[16 + si * 3 + 0], pp * vhat[(size_t)(e0 + e) * 3 + 0]);
          atomicAdd(&out[16 + si * 3 + 1], pp * vhat[(size_t)(e0 + e) * 3 + 1]);
          atomicAdd(&out[16 + si * 3 + 2], pp * vhat[(size_t)(e0 + e) * 3 + 2]);
        }
      }
    }
    __syncthreads();
  }
  if (tid < 16) atomicAdd(&out[tid], sbins[tid] * (1.f / 3600.f));
}

// ================= launcher =================
extern "C" void kernel_launch(void* const* d_in, const int* in_sizes, int n_in,
                              void* d_out, int out_size, void* d_ws, size_t ws_size,
                              hipStream_t stream) {
  (void)in_sizes; (void)n_in;
  const float* x      = (const float*)d_in[0];
  const int*   eidx   = (const int*)d_in[1];
  const int*   batch  = (const int*)d_in[2];
  const float* dist   = (const float*)d_in[3];
  const float* vhat   = (const float*)d_in[4];
  const float* rbf_w  = (const float*)d_in[5];
  const float* rbf_b  = (const float*)d_in[6];
  const float* e_in_w = (const float*)d_in[7];
  const float* e_in_b = (const float*)d_in[8];
  const float* e_hid_w = (const float*)d_in[9];
  const float* e_hid_b = (const float*)d_in[10];
  const float* e_out_w = (const float*)d_in[11];
  const float* e_out_b = (const float*)d_in[12];
  const float* f_in_w = (const float*)d_in[13];
  const float* f_in_b = (const float*)d_in[14];
  const float* f_hid_w = (const float*)d_in[15];
  const float* f_hid_b = (const float*)d_in[16];
  const float* f_out_w = (const float*)d_in[17];
  const float* f_out_b = (const float*)d_in[18];

  const size_t WP_BYTES = 17039360;               // 2 * MSTRIDE * 2B
  u16* wp       = (u16*)d_ws;
  float* wrbf_e = (float*)((char*)d_ws + WP_BYTES);
  float* wrbf_f = wrbf_e + 50 * 1024;
  float* b1_e   = wrbf_f + 50 * 1024;
  float* b1_f   = b1_e + 1024;
  const size_t BASE = WP_BYTES + 409600 + 8192;   // 17,457,152
  u16* xh   = (u16*)((char*)d_ws + BASE);                 // 8 MiB
  u16* grbf = (u16*)((char*)d_ws + BASE + 8388608);       // 8 MiB
  const size_t FIXED = BASE + 16777216;

  int nch = 0;
  for (int c = 1; c <= 8; c <<= 1) {
    size_t need = FIXED + 4 * (size_t)(NUM_E / c) * 1024 * sizeof(u16);
    if (need <= ws_size) { nch = c; break; }
  }

  hipMemsetAsync(d_out, 0, (size_t)out_size * sizeof(float), stream);
  wrbf_kernel<<<408, 256, 0, stream>>>(rbf_w, rbf_b, e_in_w, e_in_b, f_in_w, f_in_b,
                                       wrbf_e, b1_e, wrbf_f, b1_f);

  if (nch == 0) {
    packF_kernel<<<(2 * FUPM + 255) / 256, 256, 0, stream>>>(
        e_in_w, e_hid_w, f_in_w, f_hid_w, wrbf_e, wrbf_f, wp);
    fusedF_kernel<<<NUM_E / 64, 512, 0, stream>>>(x, eidx, batch, dist, vhat, wp,
                                                  b1_e, b1_f, e_hid_b, f_hid_b,
                                                  e_out_w, e_out_b, f_out_w, f_out_b,
                                                  (float*)d_out);
    return;
  }

  pack_gemm<<<1040, 256, 0, stream>>>(
      e_in_w, e_hid_w, f_in_w, f_hid_w, wrbf_e, wrbf_f, wp);
  prep_kernel<<<6144, 256, 0, stream>>>(x, dist, xh, grbf);

  const int Mchunk = NUM_E / nch;
  u16* hE0 = (u16*)((char*)d_ws + FIXED);
  u16* hE1 = hE0 + (size_t)Mchunk * 1024;
  u16* hF0 = hE1 + (size_t)Mchunk * 1024;
  u16* hF1 = hF0 + (size_t)Mchunk * 1024;
  float* out = (float*)d_out;

  for (int c = 0; c < nch; ++c) {
    int mstart = c * Mchunk;
    int grid = Mchunk / 8;    // (Mchunk/128) mt x 8 bn x 2 mlp
    gemm8k<17, 1><<<grid, 256, 0, stream>>>(
        xh, xh, grbf, eidx, batch, vhat, wp, 0,
        b1_e, b1_f, hE0, hF0, e_out_w, f_out_w, e_out_b, f_out_b, out, mstart);
    gemm8k<16, 0><<<grid, 256, 0, stream>>>(
        hE0, hF0, grbf, eidx, batch, vhat, wp, L1SZ,
        e_hid_b, f_hid_b, hE1, hF1, e_out_w, f_out_w, e_out_b, f_out_b, out, mstart);
    gemm8k<16, 0><<<grid, 256, 0, stream>>>(
        hE1, hF1, grbf, eidx, batch, vhat, wp, L1SZ + HSZ,
        e_hid_b + 1024, f_hid_b + 1024, hE0, hF0, e_out_w, f_out_w, e_out_b, f_out_b, out, mstart);
    gemm8k<16, 2><<<grid, 256, 0, stream>>>(
        hE0, hF0, grbf, eidx, batch, vhat, wp, L1SZ + 2 * HSZ,
        e_hid_b + 2048, f_hid_b + 2048, hE1, hF1, e_out_w, f_out_w, e_out_b, f_out_b, out, mstart);
  }
}

// Round 19
// 1434.407 us; speedup vs baseline: 1.0497x; 1.0497x over previous
//
#include <hip/hip_runtime.h>
#include <math.h>

#define NUM_E 65536
#define NUM_N 8192
#define NUM_G 16
#define RBFR 12.0f

typedef unsigned short u16;
typedef _Float16 f16x8 __attribute__((ext_vector_type(8)));
typedef _Float16 f16x4 __attribute__((ext_vector_type(4)));
typedef float f32x4 __attribute__((ext_vector_type(4)));

// ---------------- packed-weight geometry ----------------
#define TILE_F16 8192
#define L1SZ   1114112   // (4bn*2nh)*17kt * 8192
#define HSZ    1048576   // (4bn*2nh)*16kt * 8192 per layer
#define MSTRIDE 4259840  // L1SZ + 3*HSZ

// fused-fallback packed geometry
#define FU1  139264
#define FUHL 131072
#define FUPM (FU1 + 3 * FUHL)

#define GLD16(gp, lp) __builtin_amdgcn_global_load_lds( \
    (const __attribute__((address_space(1))) void*)(gp), \
    (__attribute__((address_space(3))) void*)(lp), 16, 0, 0)

#define VMW8()  asm volatile("s_waitcnt vmcnt(8)" ::: "memory")
#define VMW0()  asm volatile("s_waitcnt vmcnt(0)" ::: "memory")
#define BARX()  __builtin_amdgcn_s_barrier()

// ---------- pre-kernel: W_rbf = rbf_w @ in_w[1024:1536,:]; b1 folded
__global__ void wrbf_kernel(const float* __restrict__ rbf_w, const float* __restrict__ rbf_b,
                            const float* __restrict__ e_in_w, const float* __restrict__ e_in_b,
                            const float* __restrict__ f_in_w, const float* __restrict__ f_in_b,
                            float* __restrict__ wrbf_e, float* __restrict__ b1_e,
                            float* __restrict__ wrbf_f, float* __restrict__ b1_f) {
  int blk = blockIdx.x;            // 408 = 2mlp * 51row * 4ns
  int mlp = blk / 204;
  int rr = blk % 204;
  int row = rr >> 2;
  int ns = rr & 3;
  const float* in_w = mlp ? f_in_w : e_in_w;
  const float* in_b = mlp ? f_in_b : e_in_b;
  float* wrbf = mlp ? wrbf_f : wrbf_e;
  float* b1   = mlp ? b1_f : b1_e;
  __shared__ float vec[512];
  __shared__ float4 red[256];
  int tid = threadIdx.x;
  vec[tid]       = (row < 50) ? rbf_w[row * 512 + tid]       : rbf_b[tid];
  vec[tid + 256] = (row < 50) ? rbf_w[row * 512 + tid + 256] : rbf_b[tid + 256];
  __syncthreads();
  int q = tid >> 6, l = tid & 63;
  int n0 = ns * 256 + l * 4;
  float a0 = 0.f, a1 = 0.f, a2 = 0.f, a3 = 0.f;
#pragma unroll 4
  for (int c = q * 128; c < q * 128 + 128; ++c) {
    float4 wv = *(const float4*)&in_w[(size_t)(1024 + c) * 1024 + n0];
    float gv = vec[c];
    a0 += gv * wv.x; a1 += gv * wv.y; a2 += gv * wv.z; a3 += gv * wv.w;
  }
  red[tid] = float4{a0, a1, a2, a3};
  __syncthreads();
  if (q == 0) {
    float4 s0 = red[l], s1 = red[l + 64], s2 = red[l + 128], s3 = red[l + 192];
    float4 o = {s0.x + s1.x + s2.x + s3.x, s0.y + s1.y + s2.y + s3.y,
                s0.z + s1.z + s2.z + s3.z, s0.w + s1.w + s2.w + s3.w};
    if (row < 50) {
      *(float4*)&wrbf[row * 1024 + n0] = o;
    } else {
      o.x += in_b[n0]; o.y += in_b[n0 + 1]; o.z += in_b[n0 + 2]; o.w += in_b[n0 + 3];
      *(float4*)&b1[n0] = o;
    }
  }
}

// ---------- merged prep: x->f16 (bid<4096) + per-edge RBF table (else)
__global__ void prep_kernel(const float* __restrict__ x, const float* __restrict__ dist,
                            u16* __restrict__ xh, u16* __restrict__ grbf) {
  int bid = blockIdx.x, tid = threadIdx.x;
  if (bid < 4096) {
    int i = bid * 256 + tid;
    float4 v = ((const float4*)x)[i];
    f16x4 h = {(_Float16)v.x, (_Float16)v.y, (_Float16)v.z, (_Float16)v.w};
    *(f16x4*)(xh + (size_t)i * 4) = h;
  } else {
    int u = (bid - 4096) * 256 + tid;
    int e = u >> 3, q = u & 7;
    const float delta = RBFR / 49.f;
    const float coeff = -0.5f / (delta * delta);
    float d = dist[e];
    f16x8 h;
#pragma unroll
    for (int j = 0; j < 8; ++j) {
      int gi = q * 8 + j;
      float dd = d - (float)gi * delta;
      float gg = (gi < 50) ? __expf(coeff * dd * dd) : 0.f;
      h[j] = (_Float16)gg;
    }
    *(f16x8*)(grbf + (size_t)u * 8) = h;
  }
}

// ---------- weight pack v3: float4 row-coalesced reads, LDS tile build, linear dump
__global__ void pack_gemm(const float* __restrict__ e_in_w, const float* __restrict__ e_hid_w,
                          const float* __restrict__ f_in_w, const float* __restrict__ f_hid_w,
                          const float* __restrict__ wrbf_e, const float* __restrict__ wrbf_f,
                          u16* __restrict__ wp) {
  __shared__ __align__(16) u16 tile[TILE_F16];
  int bid = blockIdx.x;
  int mlpi = (bid >= 520) ? 1 : 0;
  int t = bid - mlpi * 520;
  const float* in_w  = mlpi ? f_in_w : e_in_w;
  const float* hid_w = mlpi ? f_hid_w : e_hid_w;
  const float* wrbf  = mlpi ? wrbf_f : wrbf_e;
  int tid = threadIdx.x;
  int bnp, nhp, k0, lay = 0, is_l1;
  if (t < 136) {
    int grp = t / 17; int kt = t % 17;
    bnp = grp >> 1; nhp = grp & 1; k0 = kt * 64; is_l1 = 1;
  } else {
    int th = t - 136; lay = th >> 7; int t2 = th & 127;
    bnp = t2 >> 5; nhp = (t2 >> 4) & 1; k0 = (t2 & 15) * 64; is_l1 = 0;
  }
#pragma unroll
  for (int it = 0; it < 8; ++it) {
    int flat = it * 1024 + tid * 4;      // tile elem = k*128 + nl
    int k = flat >> 7;
    int nl4 = flat & 127;
    int n0 = bnp * 256 + ((nl4 >> 5) << 6) + nhp * 32 + (nl4 & 31);
    int kg = k0 + k;
    float4 v;
    if (is_l1) {
      if (kg < 1024)      v = *(const float4*)&in_w[(size_t)kg * 1024 + n0];
      else if (kg < 1074) v = *(const float4*)&wrbf[(size_t)(kg - 1024) * 1024 + n0];
      else                v = float4{0.f, 0.f, 0.f, 0.f};
    } else {
      v = *(const float4*)&hid_w[(size_t)((lay << 10) + kg) * 1024 + n0];
    }
#pragma unroll
    for (int c = 0; c < 4; ++c) {
      int nl = nl4 + c;
      int pos = nl * 64 + ((((k >> 3) ^ (nl & 7)) << 3) | (k & 7));
      _Float16 hf = (_Float16)(((const float*)&v)[c]);
      tile[pos] = __builtin_bit_cast(u16, hf);
    }
  }
  __syncthreads();
  u16* dst = wp + (size_t)mlpi * MSTRIDE + (size_t)t * TILE_F16;
#pragma unroll
  for (int i = 0; i < 4; ++i) {
    int off = (i * 256 + tid) * 8;
    *(f16x8*)(dst + off) = *(const f16x8*)(tile + off);
  }
}

// ================= unified 256x256 GEMM, 16x16x32 MFMA =================
// MODE: 1 = layer-1 (gathered A, offsets hoisted to regs), 0 = hidden mid,
//       2 = hidden final + fused out-dot scatter.
// Schedule: 1 wait + 2 barriers per K-tile (round-17 verified best).

#define STA(b, ah, kt) do { \
  _Pragma("unroll") for (int _j = 0; _j < 2; ++_j) { \
    int _ck = wv * 2 + _j; \
    const u16* _gp; \
    if (MODE == 1) { \
      int _off = ((kt) < 8) ? (osrc[ah][_j] + (kt) * 64) \
               : (((kt) < 16) ? (odst[ah][_j] + ((kt) - 8) * 64) : ogr[ah][_j]); \
      _gp = (((kt) < 16) ? hin : grbf) + _off; \
    } else { \
      int _loc = _ck * 8 + (lane >> 3); \
      int _row = ((_loc >> 6) << 7) + (ah) * 64 + (_loc & 63); \
      int _sw = ((lane & 7) ^ (_loc & 7)) << 3; \
      _gp = hin + ((size_t)(rowb + _row) * 1024 + (kt) * 64 + _sw); \
    } \
    GLD16(_gp, (char*)&sm[b][ah][0] + _ck * 1024); \
  } \
} while (0)

#define STB(b, bh, kt) do { \
  const u16* _wt = wl + ((size_t)((bn * 2 + (bh)) * NKT + (kt))) * TILE_F16; \
  _Pragma("unroll") for (int _j = 0; _j < 2; ++_j) { \
    int _ck = wv * 2 + _j; \
    GLD16(_wt + _ck * 512 + lane * 8, (char*)&sm[b][2 + (bh)][0] + _ck * 1024); \
  } \
} while (0)

#define RDA(b, mh) do { \
  _Pragma("unroll") for (int _ks = 0; _ks < 2; ++_ks) { \
    int _kk = _ks * 4 + (lane >> 4); \
    _Pragma("unroll") for (int _m = 0; _m < 4; ++_m) { \
      int _r = wm * 64 + _m * 16 + (lane & 15); \
      af[_m][_ks] = *(const f16x8*)&sm[b][mh][_r * 64 + ((_kk ^ (_r & 7)) << 3)]; \
    } \
  } \
} while (0)

#define RDB(b, nh) do { \
  _Pragma("unroll") for (int _ks = 0; _ks < 2; ++_ks) { \
    int _kk = _ks * 4 + (lane >> 4); \
    _Pragma("unroll") for (int _n = 0; _n < 2; ++_n) { \
      int _c = wn * 32 + _n * 16 + (lane & 15); \
      bf[nh][_n][_ks] = *(const f16x8*)&sm[b][2 + (nh)][_c * 64 + ((_kk ^ (_c & 7)) << 3)]; \
    } \
  } \
} while (0)

#define PHM(mh, nh) do { \
  __builtin_amdgcn_s_setprio(1); \
  _Pragma("unroll") for (int _ks = 0; _ks < 2; ++_ks) \
    _Pragma("unroll") for (int _m = 0; _m < 4; ++_m) \
      _Pragma("unroll") for (int _n = 0; _n < 2; ++_n) \
        acc[(mh) * 4 + _m][(nh) * 2 + _n] = __builtin_amdgcn_mfma_f32_16x16x32_f16( \
            bf[nh][_n][_ks], af[_m][_ks], acc[(mh) * 4 + _m][(nh) * 2 + _n], 0, 0, 0); \
  __builtin_amdgcn_s_setprio(0); \
} while (0)

template<int NKT, int MODE>
__global__ __launch_bounds__(512, 2) void gemm8k(
    const u16* __restrict__ hinE, const u16* __restrict__ hinF,
    const u16* __restrict__ grbf, const int* __restrict__ eidx,
    const int* __restrict__ batch, const float* __restrict__ vhat,
    const u16* __restrict__ wp, size_t woff,
    const float* __restrict__ biasE, const float* __restrict__ biasF,
    u16* __restrict__ houtE, u16* __restrict__ houtF,
    const float* __restrict__ owE, const float* __restrict__ owF,
    const float* __restrict__ obE, const float* __restrict__ obF,
    float* __restrict__ out, int mstart) {
  __shared__ __align__(16) u16 sm[2][4][8192];   // 128 KiB
  __shared__ int s_src[256];
  __shared__ int s_dst[256];
  __shared__ float sred[256];
  __shared__ float sbins[16];
  const int tid = threadIdx.x;
  const int lane = tid & 63;
  const int wv = tid >> 6;
  const int wm = wv >> 2, wn = wv & 3;

  // XCD-locality decode: xcd = mt&7; bn (and mlp) siblings share the XCD.
  int mlp, mt, bn;
  {
    int xcd = blockIdx.x & 7;
    int r = blockIdx.x >> 3;
    if (MODE == 1) {
      int bnq = r & 7;
      mlp = bnq >> 2; bn = bnq & 3;
      mt = (r >> 3) * 8 + xcd;
    } else {
      bn = r & 3; mlp = (r >> 2) & 1;
      mt = (r >> 3) * 8 + xcd;
    }
  }
  const u16* hin = (MODE == 1) ? hinE : (mlp ? hinF : hinE);
  const u16* wl = wp + (size_t)mlp * MSTRIDE + woff;
  const float* bias = mlp ? biasF : biasE;
  u16* hout = mlp ? houtF : houtE;
  const int rowb = mt * 256;
  const int n0 = bn * 256;
  const int eg0 = mstart + rowb;

  int osrc[2][2], odst[2][2], ogr[2][2];
  if (MODE == 1) {
    if (tid < 256) s_src[tid] = eidx[eg0 + tid];
    else s_dst[tid - 256] = eidx[NUM_E + eg0 + tid - 256];
    __syncthreads();
#pragma unroll
    for (int ah = 0; ah < 2; ++ah) {
#pragma unroll
      for (int j = 0; j < 2; ++j) {
        int ck = wv * 2 + j;
        int loc = ck * 8 + (lane >> 3);
        int row = ((loc >> 6) << 7) + ah * 64 + (loc & 63);
        int sw = ((lane & 7) ^ (loc & 7)) << 3;
        osrc[ah][j] = s_src[row] * 512 + sw;
        odst[ah][j] = s_dst[row] * 512 + sw;
        ogr[ah][j]  = (eg0 + row) * 64 + sw;
      }
    }
  }

  f32x4 acc[8][4];
#pragma unroll
  for (int m = 0; m < 8; ++m)
#pragma unroll
    for (int n = 0; n < 4; ++n)
#pragma unroll
      for (int i = 0; i < 4; ++i) acc[m][n][i] = 0.f;

  f16x8 af[4][2], bf[2][2][2];

  // prologue: stage tile 0 (8 glds); retirement handled by first loop iter's VMW8
  STA(0, 0, 0); STB(0, 0, 0); STB(0, 1, 0); STA(0, 1, 0);

  for (int t = 0; t < NKT - 1; ++t) {
    const int b = t & 1, nb = b ^ 1;
    // stage whole next tile; outstanding 8(t) + 8(t+1) = 16
    STA(nb, 0, t + 1); STB(nb, 0, t + 1); STB(nb, 1, t + 1); STA(nb, 1, t + 1);
    VMW8(); BARX();           // retire exactly tile t; whole buffer b visible
    RDA(b, 0); RDB(b, 0);
    PHM(0, 0);
    RDB(b, 1);
    PHM(0, 1);
    RDA(b, 1);
    PHM(1, 0);
    PHM(1, 1);
    BARX();                   // all reads of b done before next iter stages b
  }
  // tail tile NKT-1 (outstanding = 8, its glds)
  {
    const int tb = (NKT - 1) & 1;
    VMW0(); BARX();
    RDA(tb, 0); RDB(tb, 0); PHM(0, 0);
    RDB(tb, 1); PHM(0, 1);
    RDA(tb, 1); PHM(1, 0); PHM(1, 1);
  }

  if (MODE != 2) {
    // epilogue: bias + silu (+ residual for hidden), store f16
#pragma unroll
    for (int mi = 0; mi < 8; ++mi) {
#pragma unroll
      for (int ni = 0; ni < 4; ++ni) {
        int grow = rowb + wm * 128 + mi * 16 + (lane & 15);
        int gn = n0 + wn * 64 + ni * 16 + ((lane >> 4) << 2);
        float4 bi = *(const float4*)&bias[gn];
        f16x4 o;
        if (MODE == 1) {
#pragma unroll
          for (int i = 0; i < 4; ++i) {
            float pre = acc[mi][ni][i] + ((const float*)&bi)[i];
            o[i] = (_Float16)(pre / (1.f + __expf(-pre)));
          }
        } else {
          f16x4 hp = *(const f16x4*)&hin[(size_t)grow * 1024 + gn];
#pragma unroll
          for (int i = 0; i < 4; ++i) {
            float pre = acc[mi][ni][i] + ((const float*)&bi)[i];
            o[i] = (_Float16)(pre / (1.f + __expf(-pre)) + (float)hp[i]);
          }
        }
        *(f16x4*)&hout[(size_t)grow * 1024 + gn] = o;
      }
    }
  } else {
    // fused final epilogue: silu+residual, dot with out_w, reduce, scatter
    if (tid < 256) sred[tid] = 0.f;
    if (tid < 16) sbins[tid] = 0.f;
    __syncthreads();
    const float* ow = mlp ? owF : owE;
    float p[8];
#pragma unroll
    for (int mi = 0; mi < 8; ++mi) p[mi] = 0.f;
#pragma unroll
    for (int mi = 0; mi < 8; ++mi) {
#pragma unroll
      for (int ni = 0; ni < 4; ++ni) {
        int grow = rowb + wm * 128 + mi * 16 + (lane & 15);
        int gn = n0 + wn * 64 + ni * 16 + ((lane >> 4) << 2);
        float4 bi = *(const float4*)&bias[gn];
        float4 wv4 = *(const float4*)&ow[gn];
        f16x4 hp = *(const f16x4*)&hin[(size_t)grow * 1024 + gn];
#pragma unroll
        for (int i = 0; i < 4; ++i) {
          float pre = acc[mi][ni][i] + ((const float*)&bi)[i];
          float val = pre / (1.f + __expf(-pre)) + (float)hp[i];
          p[mi] += val * ((const float*)&wv4)[i];
        }
      }
    }
#pragma unroll
    for (int mi = 0; mi < 8; ++mi) {
      p[mi] += __shfl_down(p[mi], 32, 64);
      p[mi] += __shfl_down(p[mi], 16, 64);
    }
    if ((lane >> 4) == 0) {
#pragma unroll
      for (int mi = 0; mi < 8; ++mi)
        atomicAdd(&sred[wm * 128 + mi * 16 + (lane & 15)], p[mi]);
    }
    __syncthreads();
    if (tid < 256) {
      float s = sred[tid];
      int eg = eg0 + tid;
      int si = eidx[eg];
      if (mlp == 0) {
        float pv = s + ((bn == 0) ? obE[0] : 0.f);
        atomicAdd(&sbins[batch[si]], pv);
      } else {
        float pv = (s + ((bn == 0) ? obF[0] : 0.f)) * (1.f / 60.f);
        atomicAdd(&out[16 + si * 3 + 0], pv * vhat[(size_t)eg * 3 + 0]);
        atomicAdd(&out[16 + si * 3 + 1], pv * vhat[(size_t)eg * 3 + 1]);
        atomicAdd(&out[16 + si * 3 + 2], pv * vhat[(size_t)eg * 3 + 2]);
      }
    }
    __syncthreads();
    if (mlp == 0 && tid < 16) atomicAdd(&out[tid], sbins[tid] * (1.f / 3600.f));
  }
}

// ================= fused fallback (only if ws too small) =================
#define FSWZ(row, col) ((((row) * 1088) + (col)) ^ (((row) & 7) << 3))

__global__ void packF_kernel(const float* __restrict__ e_in_w, const float* __restrict__ e_hid_w,
                             const float* __restrict__ f_in_w, const float* __restrict__ f_hid_w,
                             const float* __restrict__ wrbf_e, const float* __restrict__ wrbf_f,
                             u16* __restrict__ wp) {
  int u = blockIdx.x * 256 + threadIdx.x;
  if (u >= 2 * FUPM) return;
  int m = (u >= FUPM) ? 1 : 0;
  int v = u - m * FUPM;
  const float* in_w  = m ? f_in_w : e_in_w;
  const float* hid_w = m ? f_hid_w : e_hid_w;
  const float* wrbf  = m ? wrbf_f : wrbf_e;
  int l = v & 63;
  int kb = (l >> 4) << 3;
  f16x8 vals;
  if (v < FU1) {
    int kt = v >> 12;
    int ntg = (v >> 6) & 63;
    int n = ntg * 16 + (l & 15);
    int k0 = kt * 32 + kb;
#pragma unroll
    for (int jj = 0; jj < 8; ++jj) {
      int k = k0 + jj;
      float f = (k < 1024) ? in_w[(size_t)k * 1024 + n]
              : ((k < 1074) ? wrbf[(k - 1024) * 1024 + n] : 0.f);
      vals[jj] = (_Float16)f;
    }
  } else {
    int vh = v - FU1;
    int lay = vh >> 17;
    int kt = (vh >> 12) & 31;
    int ntg = (vh >> 6) & 63;
    int n = ntg * 16 + (l & 15);
    int k0 = kt * 32 + kb;
#pragma unroll
    for (int jj = 0; jj < 8; ++jj)
      vals[jj] = (_Float16)hid_w[(size_t)((lay << 10) + k0 + jj) * 1024 + n];
  }
  *(f16x8*)(wp + (size_t)u * 8) = vals;
}

#define F_LOADB(buf, kt) do { \
  const u16* _wr = wl + ((size_t)((kt) * 64 + wave * 8) * 64 + lane) * 8; \
  _Pragma("unroll") \
  for (int _nt = 0; _nt < 8; ++_nt) buf[_nt] = *(const f16x8*)(_wr + (size_t)_nt * 512); \
} while (0)
#define F_LOADA(buf, kt) do { \
  const int _kb = (kt) * 32 + ((lane >> 4) << 3); \
  _Pragma("unroll") \
  for (int _r = 0; _r < 4; ++_r) buf[_r] = *(const f16x8*)&Alds[FSWZ(_r * 16 + (lane & 15), _kb)]; \
} while (0)
#define F_MFMAS(abuf, bbuf) do { \
  _Pragma("unroll") \
  for (int _nt = 0; _nt < 8; ++_nt) \
    _Pragma("unroll") \
    for (int _r = 0; _r < 4; ++_r) \
      acc[_r][_nt] = __builtin_amdgcn_mfma_f32_16x16x32_f16(abuf[_r], bbuf[_nt], acc[_r][_nt], 0, 0, 0); \
} while (0)

__global__ __launch_bounds__(512, 2) void fusedF_kernel(
    const float* __restrict__ x, const int* __restrict__ eidx,
    const int* __restrict__ batch, const float* __restrict__ dist,
    const float* __restrict__ vhat,
    const u16* __restrict__ wp,
    const float* __restrict__ b1_e, const float* __restrict__ b1_f,
    const float* __restrict__ e_hid_b, const float* __restrict__ f_hid_b,
    const float* __restrict__ e_out_w, const float* __restrict__ e_out_b,
    const float* __restrict__ f_out_w, const float* __restrict__ f_out_b,
    float* __restrict__ out) {
  __shared__ __align__(16) u16 Alds[64 * 1088];
  __shared__ float sow[1024];
  __shared__ float sbins[16];
  __shared__ int s_src[64];
  __shared__ int s_dst[64];
  __shared__ float s_dist[64];
  const int tid = threadIdx.x;
  const int lane = tid & 63;
  const int wave = tid >> 6;
  const int e0 = blockIdx.x * 64;
  if (tid < 16) sbins[tid] = 0.f;
  if (tid < 64) s_src[tid] = eidx[e0 + tid];
  if (tid >= 64 && tid < 128) s_dst[tid - 64] = eidx[NUM_E + e0 + tid - 64];
  if (tid >= 128 && tid < 192) s_dist[tid - 128] = dist[e0 + tid - 128];
  __syncthreads();
  const float delta = RBFR / 49.f;
  const float coeff = -0.5f / (delta * delta);
  for (int mlp = 0; mlp < 2; ++mlp) {
    for (int i = tid; i < 16384; i += 512) {
      int e = i >> 8;
      int part = (i >> 7) & 1;
      int q = i & 127;
      int nrow = part ? s_dst[e] : s_src[e];
      float4 v = ((const float4*)x)[(size_t)nrow * 128 + q];
      int col = part * 512 + q * 4;
      f16x4 hv = {(_Float16)v.x, (_Float16)v.y, (_Float16)v.z, (_Float16)v.w};
      *(f16x4*)&Alds[FSWZ(e, col)] = hv;
    }
    for (int i = tid; i < 4096; i += 512) {
      int e = i >> 6;
      int gi = i & 63;
      float d = s_dist[e] - (float)gi * delta;
      float g2 = (gi < 50) ? __expf(coeff * d * d) : 0.f;
      _Float16 hg = (_Float16)g2;
      Alds[FSWZ(e, 1024 + gi)] = __builtin_bit_cast(u16, hg);
    }
    __syncthreads();
    const u16* wp1 = wp + (size_t)mlp * FUPM * 8;
    const u16* wph = wp1 + (size_t)FU1 * 8;
    const float* b1 = mlp ? b1_f : b1_e;
    const float* hb = mlp ? f_hid_b : e_hid_b;
    for (int layer = 0; layer < 4; ++layer) {
      const int nkt = (layer == 0) ? 34 : 32;
      const u16* wl = (layer == 0) ? wp1 : (wph + (size_t)(layer - 1) * FUHL * 8);
      const float* bias = (layer == 0) ? b1 : (hb + (layer - 1) * 1024);
      f32x4 acc[4][8];
#pragma unroll
      for (int r = 0; r < 4; ++r)
#pragma unroll
        for (int nt = 0; nt < 8; ++nt)
#pragma unroll
          for (int i = 0; i < 4; ++i) acc[r][nt][i] = 0.f;
      f16x8 a0[4], a1[4], b0[8], b1r[8];
      F_LOADA(a0, 0); F_LOADB(b0, 0);
      F_LOADA(a1, 1); F_LOADB(b1r, 1);
      for (int kt = 0; kt < nkt; kt += 2) {
        F_MFMAS(a0, b0);
        if (kt + 2 < nkt) { F_LOADA(a0, kt + 2); F_LOADB(b0, kt + 2); }
        F_MFMAS(a1, b1r);
        if (kt + 3 < nkt) { F_LOADA(a1, kt + 3); F_LOADB(b1r, kt + 3); }
      }
      __syncthreads();
      float bia[8];
#pragma unroll
      for (int nt = 0; nt < 8; ++nt) bia[nt] = bias[wave * 128 + nt * 16 + (lane & 15)];
#pragma unroll
      for (int r = 0; r < 4; ++r) {
#pragma unroll
        for (int nt = 0; nt < 8; ++nt) {
#pragma unroll
          for (int i = 0; i < 4; ++i) {
            int row = r * 16 + ((lane >> 4) << 2) + i;
            int col = wave * 128 + nt * 16 + (lane & 15);
            float pre = acc[r][nt][i] + bia[nt];
            float val = pre / (1.f + __expf(-pre));
            int idx = FSWZ(row, col);
            if (layer > 0) {
              _Float16 oldh = __builtin_bit_cast(_Float16, Alds[idx]);
              val += (float)oldh;
            }
            _Float16 nh = (_Float16)val;
            Alds[idx] = __builtin_bit_cast(u16, nh);
          }
        }
      }
      __syncthreads();
    }
    const float* ow = mlp ? f_out_w : e_out_w;
    for (int i = tid; i < 1024; i += 512) sow[i] = ow[i];
    __syncthreads();
    {
      int e = tid >> 3;
      int part = tid & 7;
      float s = 0.f;
#pragma unroll
      for (int cc = 0; cc < 16; ++cc) {
        int col = part * 128 + cc * 8;
        f16x8 hv = *(const f16x8*)&Alds[FSWZ(e, col)];
#pragma unroll
        for (int q = 0; q < 8; ++q) s += (float)hv[q] * sow[col + q];
      }
      s += __shfl_down(s, 4, 8);
      s += __shfl_down(s, 2, 8);
      s += __shfl_down(s, 1, 8);
      if (part == 0) {
        if (mlp == 0) {
          float pp = s + e_out_b[0];
          int gg = batch[s_src[e]];
          atomicAdd(&sbins[gg], pp);
        } else {
          float pp = (s + f_out_b[0]) * (1.f / 60.f);
          int si = s_src[e];
          atomicAdd(&out[16 + si * 3 + 0], pp * vhat[(size_t)(e0 + e) * 3 + 0]);
          atomicAdd(&out[16 + si * 3 + 1], pp * vhat[(size_t)(e0 + e) * 3 + 1]);
          atomicAdd(&out[16 + si * 3 + 2], pp * vhat[(size_t)(e0 + e) * 3 + 2]);
        }
      }
    }
    __syncthreads();
  }
  if (tid < 16) atomicAdd(&out[tid], sbins[tid] * (1.f / 3600.f));
}

// ================= launcher =================
extern "C" void kernel_launch(void* const* d_in, const int* in_sizes, int n_in,
                              void* d_out, int out_size, void* d_ws, size_t ws_size,
                              hipStream_t stream) {
  (void)in_sizes; (void)n_in;
  const float* x      = (const float*)d_in[0];
  const int*   eidx   = (const int*)d_in[1];
  const int*   batch  = (const int*)d_in[2];
  const float* dist   = (const float*)d_in[3];
  const float* vhat   = (const float*)d_in[4];
  const float* rbf_w  = (const float*)d_in[5];
  const float* rbf_b  = (const float*)d_in[6];
  const float* e_in_w = (const float*)d_in[7];
  const float* e_in_b = (const float*)d_in[8];
  const float* e_hid_w = (const float*)d_in[9];
  const float* e_hid_b = (const float*)d_in[10];
  const float* e_out_w = (const float*)d_in[11];
  const float* e_out_b = (const float*)d_in[12];
  const float* f_in_w = (const float*)d_in[13];
  const float* f_in_b = (const float*)d_in[14];
  const float* f_hid_w = (const float*)d_in[15];
  const float* f_hid_b = (const float*)d_in[16];
  const float* f_out_w = (const float*)d_in[17];
  const float* f_out_b = (const float*)d_in[18];

  const size_t WP_BYTES = 17039360;               // 2 * MSTRIDE * 2B
  u16* wp       = (u16*)d_ws;
  float* wrbf_e = (float*)((char*)d_ws + WP_BYTES);
  float* wrbf_f = wrbf_e + 50 * 1024;
  float* b1_e   = wrbf_f + 50 * 1024;
  float* b1_f   = b1_e + 1024;
  const size_t BASE = WP_BYTES + 409600 + 8192;   // 17,457,152
  u16* xh   = (u16*)((char*)d_ws + BASE);                 // 8 MiB
  u16* grbf = (u16*)((char*)d_ws + BASE + 8388608);       // 8 MiB
  const size_t FIXED = BASE + 16777216;

  int nch = 0;
  for (int c = 1; c <= 8; c <<= 1) {
    size_t need = FIXED + 4 * (size_t)(NUM_E / c) * 1024 * sizeof(u16);
    if (need <= ws_size) { nch = c; break; }
  }

  hipMemsetAsync(d_out, 0, (size_t)out_size * sizeof(float), stream);
  wrbf_kernel<<<408, 256, 0, stream>>>(rbf_w, rbf_b, e_in_w, e_in_b, f_in_w, f_in_b,
                                       wrbf_e, b1_e, wrbf_f, b1_f);

  if (nch == 0) {
    packF_kernel<<<(2 * FUPM + 255) / 256, 256, 0, stream>>>(
        e_in_w, e_hid_w, f_in_w, f_hid_w, wrbf_e, wrbf_f, wp);
    fusedF_kernel<<<NUM_E / 64, 512, 0, stream>>>(x, eidx, batch, dist, vhat, wp,
                                                  b1_e, b1_f, e_hid_b, f_hid_b,
                                                  e_out_w, e_out_b, f_out_w, f_out_b,
                                                  (float*)d_out);
    return;
  }

  pack_gemm<<<1040, 256, 0, stream>>>(
      e_in_w, e_hid_w, f_in_w, f_hid_w, wrbf_e, wrbf_f, wp);
  prep_kernel<<<6144, 256, 0, stream>>>(x, dist, xh, grbf);

  const int Mchunk = NUM_E / nch;
  u16* hE0 = (u16*)((char*)d_ws + FIXED);
  u16* hE1 = hE0 + (size_t)Mchunk * 1024;
  u16* hF0 = hE1 + (size_t)Mchunk * 1024;
  u16* hF1 = hF0 + (size_t)Mchunk * 1024;
  float* out = (float*)d_out;

  for (int c = 0; c < nch; ++c) {
    int mstart = c * Mchunk;
    int grid = Mchunk / 32;
    gemm8k<17, 1><<<grid, 512, 0, stream>>>(
        xh, xh, grbf, eidx, batch, vhat, wp, 0,
        b1_e, b1_f, hE0, hF0, e_out_w, f_out_w, e_out_b, f_out_b, out, mstart);
    gemm8k<16, 0><<<grid, 512, 0, stream>>>(
        hE0, hF0, grbf, eidx, batch, vhat, wp, L1SZ,
        e_hid_b, f_hid_b, hE1, hF1, e_out_w, f_out_w, e_out_b, f_out_b, out, mstart);
    gemm8k<16, 0><<<grid, 512, 0, stream>>>(
        hE1, hF1, grbf, eidx, batch, vhat, wp, L1SZ + HSZ,
        e_hid_b + 1024, f_hid_b + 1024, hE0, hF0, e_out_w, f_out_w, e_out_b, f_out_b, out, mstart);
    gemm8k<16, 2><<<grid, 512, 0, stream>>>(
        hE0, hF0, grbf, eidx, batch, vhat, wp, L1SZ + 2 * HSZ,
        e_hid_b + 2048, f_hid_b + 2048, hE1, hF1, e_out_w, f_out_w, e_out_b, f_out_b, out, mstart);
  }
}